// Round 6
// baseline (268.475 us; speedup 1.0000x reference)
//
#include <hip/hip_runtime.h>
#include <hip/hip_bf16.h>
#include <hip/hip_cooperative_groups.h>

namespace cg = cooperative_groups;

#define EMB 64

typedef __attribute__((ext_vector_type(8))) short short8;
typedef __attribute__((ext_vector_type(8))) __bf16 bf16x8;
typedef __attribute__((ext_vector_type(4))) float f32x4;

__device__ inline f32x4 mfma16x16x32(short8 a, short8 b, f32x4 c) {
  return __builtin_amdgcn_mfma_f32_16x16x32_bf16(
      __builtin_bit_cast(bf16x8, a), __builtin_bit_cast(bf16x8, b), c, 0, 0, 0);
}

// Raw v_exp_f32 (2^x). OCML exp2f/__expf are multi-instr expansions (r2-r4 lesson).
#define EXP2_HW __builtin_amdgcn_exp2f
#define C5LOG2E 7.213475204444817f  // 5 * log2(e)

// One cooperative kernel, 512 blocks x 256 threads (2 blocks/CU guaranteed
// co-resident at <=256 VGPR). Phases separated by grid.sync():
//  1) prep: 16 rows/block (stride-512): gather, l2-normalize, bf16 store,
//     per-row 'up' term, first-occurrence scan for nu/ni (no flag arrays).
//  2) gemm: 64 row-tiles x 8 col-strips; A-frags loaded once, 8 tiles reused;
//     fused exp-sum epilogue in registers.
//  3) block 0 reduces 512 partials -> out[2].
__global__ __launch_bounds__(256, 2) void fused_kernel(
    const int* __restrict__ user, const int* __restrict__ pos,
    const float* __restrict__ uw, const float* __restrict__ iw,
    __hip_bfloat16* __restrict__ u_bf, __hip_bfloat16* __restrict__ p_bf,
    float* __restrict__ up_p, float* __restrict__ dn_p,
    int* __restrict__ uc_p, int* __restrict__ ic_p,
    float* __restrict__ out)
{
  cg::grid_group grid = cg::this_grid();
  const int tid  = threadIdx.x;
  const int wave = tid >> 6;
  const int lane = tid & 63;
  const int blk  = blockIdx.x;

  // ---------------- Phase 1: prep ----------------
  float upacc = 0.0f;
  int   ucnt  = 0, icnt = 0;

  #pragma unroll 1
  for (int ii = 0; ii < 4; ++ii) {
    const int row  = blk + (((wave << 2) + ii) << 9);   // blk + 512*(wave*4+ii)
    const int uidx = user[row];
    const int pidx = pos[row];
    float uv = uw[uidx * EMB + lane];
    float pv = iw[pidx * EMB + lane];

    float us = uv * uv, ps = pv * pv;
    #pragma unroll
    for (int off = 32; off; off >>= 1) {
      us += __shfl_xor(us, off);
      ps += __shfl_xor(ps, off);
    }
    const float un = uv / fmaxf(sqrtf(us), 1e-12f);
    const float pn = pv / fmaxf(sqrtf(ps), 1e-12f);
    u_bf[row * EMB + lane] = __float2bfloat16(un);
    p_bf[row * EMB + lane] = __float2bfloat16(pn);

    float ipv = un * pn;
    #pragma unroll
    for (int off = 32; off; off >>= 1) ipv += __shfl_xor(ipv, off);

    if (lane == 0) {
      const float t = ipv * C5LOG2E;
      upacc += logf(EXP2_HW(t) + EXP2_HW(ipv * t));  // log(exp(ip/T)+exp(ip^2/T))
    }

    // First-occurrence scan: row contributes 1 to nu iff no earlier row has
    // the same user id (ditto items). Wave-parallel over 64-chunks.
    bool udup = false, idup = false;
    const int nfull = row >> 6;
    #pragma unroll 1
    for (int c = 0; c < nfull; ++c) {
      udup |= (user[(c << 6) + lane] == uidx);
      idup |= (pos [(c << 6) + lane] == pidx);
    }
    const int base = nfull << 6;   // base+lane <= 8191 always
    if (base + lane < row) {
      udup |= (user[base + lane] == uidx);
      idup |= (pos [base + lane] == pidx);
    }
    ucnt += __any(udup) ? 0 : 1;   // wave-uniform
    icnt += __any(idup) ? 0 : 1;
  }

  __shared__ float sredf[4];
  __shared__ int   sredu[4], sredi[4];
  if (lane == 0) { sredf[wave] = upacc; sredu[wave] = ucnt; sredi[wave] = icnt; }
  __syncthreads();
  if (tid == 0) {
    up_p[blk] = (sredf[0] + sredf[1]) + (sredf[2] + sredf[3]);
    uc_p[blk] = sredu[0] + sredu[1] + sredu[2] + sredu[3];
    ic_p[blk] = sredi[0] + sredi[1] + sredi[2] + sredi[3];
  }

  __threadfence();   // device-scope release (cross-XCD visibility of u_bf/p_bf)
  grid.sync();

  // ---------------- Phase 2: gemm + exp-sum ----------------
  {
    const int by = blk >> 3;
    const int cs = blk & 7;
    const int r0 = by * 128 + (wave >> 1) * 64;
    const int lrow = lane & 15;
    const int lk   = (lane >> 4) * 8;

    short8 a[4][2];
    #pragma unroll
    for (int i = 0; i < 4; ++i)
      #pragma unroll
      for (int kk = 0; kk < 2; ++kk)
        a[i][kk] = *reinterpret_cast<const short8*>(
            &u_bf[(size_t)(r0 + i * 16 + lrow) * EMB + kk * 32 + lk]);

    float s0 = 0.0f, s1 = 0.0f;

    #pragma unroll 1
    for (int t = 0; t < 8; ++t) {
      const int c0 = (cs * 8 + t) * 128 + (wave & 1) * 64;

      short8 b[4][2];
      #pragma unroll
      for (int j = 0; j < 4; ++j)
        #pragma unroll
        for (int kk = 0; kk < 2; ++kk)
          b[j][kk] = *reinterpret_cast<const short8*>(
              &p_bf[(size_t)(c0 + j * 16 + lrow) * EMB + kk * 32 + lk]);

      f32x4 acc[4][4] = {};
      #pragma unroll
      for (int i = 0; i < 4; ++i)
        #pragma unroll
        for (int j = 0; j < 4; ++j) {
          acc[i][j] = mfma16x16x32(a[i][0], b[j][0], acc[i][j]);
          acc[i][j] = mfma16x16x32(a[i][1], b[j][1], acc[i][j]);
        }

      // exp(v/T) = 2^(v*C); exp(v^2/T) = 2^(v*(v*C)); |v| <= ~1.
      #pragma unroll
      for (int i = 0; i < 4; ++i)
        #pragma unroll
        for (int j = 0; j < 4; ++j)
          #pragma unroll
          for (int r = 0; r < 4; ++r) {
            const float v  = acc[i][j][r];
            const float tt = v * C5LOG2E;
            s0 += EXP2_HW(tt);
            s1 += EXP2_HW(v * tt);
          }
    }

    float s = s0 + s1;
    #pragma unroll
    for (int off = 32; off; off >>= 1) s += __shfl_xor(s, off);

    __syncthreads();           // re-use sredf
    if (lane == 0) sredf[wave] = s;
    __syncthreads();
    if (tid == 0)
      dn_p[blk] = (sredf[0] + sredf[1]) + (sredf[2] + sredf[3]);
  }

  __threadfence();
  grid.sync();

  // ---------------- Phase 3: final reduce (block 0) ----------------
  if (blk == 0) {
    float upv = up_p[tid] + up_p[tid + 256];
    float dnv = dn_p[tid] + dn_p[tid + 256];
    int   uc  = uc_p[tid] + uc_p[tid + 256];
    int   ic  = ic_p[tid] + ic_p[tid + 256];

    #pragma unroll
    for (int off = 32; off; off >>= 1) {
      upv += __shfl_xor(upv, off);
      dnv += __shfl_xor(dnv, off);
      uc  += __shfl_xor(uc, off);
      ic  += __shfl_xor(ic, off);
    }

    __shared__ float ff[2][4];
    __shared__ int   gg[2][4];
    __syncthreads();
    if (lane == 0) { ff[0][wave] = upv; ff[1][wave] = dnv; gg[0][wave] = uc; gg[1][wave] = ic; }
    __syncthreads();
    if (tid == 0) {
      const float usum = (ff[0][0] + ff[0][1]) + (ff[0][2] + ff[0][3]);
      const float dsum = (ff[1][0] + ff[1][1]) + (ff[1][2] + ff[1][3]);
      const int   nu   = gg[0][0] + gg[0][1] + gg[0][2] + gg[0][3];
      const int   ni   = gg[1][0] + gg[1][1] + gg[1][2] + gg[1][3];
      out[0] = -(usum / 8192.0f);
      out[1] = logf(dsum / ((float)nu * (float)ni));
    }
  }
}

extern "C" void kernel_launch(void* const* d_in, const int* in_sizes, int n_in,
                              void* d_out, int out_size, void* d_ws, size_t ws_size,
                              hipStream_t stream) {
  const int*   user = (const int*)d_in[0];
  const int*   pos  = (const int*)d_in[1];
  // d_in[2] = negative (unused by the reference loss)
  const float* uw   = (const float*)d_in[3];
  const float* iw   = (const float*)d_in[4];
  float* out = (float*)d_out;

  char* ws = (char*)d_ws;
  __hip_bfloat16* u_bf = (__hip_bfloat16*)(ws);
  __hip_bfloat16* p_bf = (__hip_bfloat16*)(ws + (1u << 20));
  float* up_p = (float*)(ws + (2u << 20));
  float* dn_p = up_p + 512;
  int*   uc_p = (int*)(dn_p + 512);
  int*   ic_p = uc_p + 512;

  void* args[] = { (void*)&user, (void*)&pos, (void*)&uw, (void*)&iw,
                   (void*)&u_bf, (void*)&p_bf,
                   (void*)&up_p, (void*)&dn_p, (void*)&uc_p, (void*)&ic_p,
                   (void*)&out };
  hipLaunchCooperativeKernel((const void*)fused_kernel,
                             dim3(512), dim3(256), args, 0, stream);
}

// Round 8
// 268.440 us; speedup vs baseline: 1.0001x; 1.0001x over previous
//
#include <hip/hip_runtime.h>
#include <hip/hip_bf16.h>
#include <hip/hip_cooperative_groups.h>

namespace cg = cooperative_groups;

#define EMB 64

typedef __attribute__((ext_vector_type(8))) short short8;
typedef __attribute__((ext_vector_type(8))) __bf16 bf16x8;
typedef __attribute__((ext_vector_type(4))) float f32x4;

__device__ inline f32x4 mfma16x16x32(short8 a, short8 b, f32x4 c) {
  return __builtin_amdgcn_mfma_f32_16x16x32_bf16(
      __builtin_bit_cast(bf16x8, a), __builtin_bit_cast(bf16x8, b), c, 0, 0, 0);
}

// Raw v_exp_f32 (2^x). OCML exp2f/__expf are multi-instr expansions (r2-r4 lesson).
#define EXP2_HW __builtin_amdgcn_exp2f
#define C5LOG2E 7.213475204444817f  // 5 * log2(e)

// ---------------------------------------------------------------------------
// Fused cooperative kernel: 512 blocks x 256 threads. Phase 2 kept at the
// EXACT r6 register shape (64 VGPR, proven 2-blocks/CU co-resident) — r7's
// double-buffer variant grew registers and the coop launch silently failed
// (out stayed all-zero == round-0 signature). Flags+popcount dedup kept
// (r6's O(B^2) scan was a 235 us latency disaster).
// ---------------------------------------------------------------------------
__global__ __launch_bounds__(256, 2) void fused_kernel(
    const int* __restrict__ user, const int* __restrict__ pos,
    const float* __restrict__ uw, const float* __restrict__ iw,
    __hip_bfloat16* __restrict__ u_bf, __hip_bfloat16* __restrict__ p_bf,
    uint4* __restrict__ flag4,          // 12500 uint4: [0,6250)=user, [6250,12500)=item
    float* __restrict__ up_p, float* __restrict__ dn_p,
    int* __restrict__ uc_p, int* __restrict__ ic_p,
    float* __restrict__ out)
{
  cg::grid_group grid = cg::this_grid();
  const int tid  = threadIdx.x;
  const int wave = tid >> 6;
  const int lane = tid & 63;
  const int blk  = blockIdx.x;

  unsigned char* uflag = (unsigned char*)flag4;
  unsigned char* iflag = uflag + 100000;

  __shared__ float sredf[4];
  __shared__ int   sredi[4];

  // ---------------- Phase 0: clear flags ----------------
  {
    const int i = blk * 256 + tid;
    if (i < 12500) flag4[i] = make_uint4(0u, 0u, 0u, 0u);
  }
  grid.sync();

  // ---------------- Phase 1: prep ----------------
  float upacc = 0.0f;
  #pragma unroll 1
  for (int ii = 0; ii < 4; ++ii) {
    const int row  = blk + (((wave << 2) + ii) << 9);   // blk + 512*(wave*4+ii)
    const int uidx = user[row];
    const int pidx = pos[row];
    float uv = uw[uidx * EMB + lane];
    float pv = iw[pidx * EMB + lane];

    float us = uv * uv, ps = pv * pv;
    #pragma unroll
    for (int off = 32; off; off >>= 1) {
      us += __shfl_xor(us, off);
      ps += __shfl_xor(ps, off);
    }
    const float un = uv / fmaxf(sqrtf(us), 1e-12f);
    const float pn = pv / fmaxf(sqrtf(ps), 1e-12f);
    u_bf[row * EMB + lane] = __float2bfloat16(un);
    p_bf[row * EMB + lane] = __float2bfloat16(pn);

    float ipv = un * pn;
    #pragma unroll
    for (int off = 32; off; off >>= 1) ipv += __shfl_xor(ipv, off);

    if (lane == 0) {
      uflag[uidx] = 1;
      iflag[pidx] = 1;
      const float t = ipv * C5LOG2E;
      upacc += logf(EXP2_HW(t) + EXP2_HW(ipv * t));  // log(exp(ip/T)+exp(ip^2/T))
    }
  }

  if (lane == 0) sredf[wave] = upacc;
  __syncthreads();
  if (tid == 0)
    up_p[blk] = (sredf[0] + sredf[1]) + (sredf[2] + sredf[3]);

  __threadfence();   // device-scope release (u_bf/p_bf/flags cross-XCD)
  grid.sync();

  // ---------------- Phase 2: gemm + exp-sum (r6 shape), then popcount ----------------
  {
    const int by = blk >> 3;
    const int cs = blk & 7;
    const int r0 = by * 128 + (wave >> 1) * 64;
    const int lrow = lane & 15;
    const int lk   = (lane >> 4) * 8;

    short8 a[4][2];
    #pragma unroll
    for (int i = 0; i < 4; ++i)
      #pragma unroll
      for (int kk = 0; kk < 2; ++kk)
        a[i][kk] = *reinterpret_cast<const short8*>(
            &u_bf[(size_t)(r0 + i * 16 + lrow) * EMB + kk * 32 + lk]);

    float s0 = 0.0f, s1 = 0.0f;

    #pragma unroll 1
    for (int t = 0; t < 8; ++t) {
      const int c0 = (cs * 8 + t) * 128 + (wave & 1) * 64;

      short8 b[4][2];
      #pragma unroll
      for (int j = 0; j < 4; ++j)
        #pragma unroll
        for (int kk = 0; kk < 2; ++kk)
          b[j][kk] = *reinterpret_cast<const short8*>(
              &p_bf[(size_t)(c0 + j * 16 + lrow) * EMB + kk * 32 + lk]);

      f32x4 acc[4][4] = {};
      #pragma unroll
      for (int i = 0; i < 4; ++i)
        #pragma unroll
        for (int j = 0; j < 4; ++j) {
          acc[i][j] = mfma16x16x32(a[i][0], b[j][0], acc[i][j]);
          acc[i][j] = mfma16x16x32(a[i][1], b[j][1], acc[i][j]);
        }

      // exp(v/T) = 2^(v*C); exp(v^2/T) = 2^(v*(v*C)); |v| <= ~1.
      #pragma unroll
      for (int i = 0; i < 4; ++i)
        #pragma unroll
        for (int j = 0; j < 4; ++j)
          #pragma unroll
          for (int r = 0; r < 4; ++r) {
            const float v  = acc[i][j][r];
            const float tt = v * C5LOG2E;
            s0 += EXP2_HW(tt);
            s1 += EXP2_HW(v * tt);
          }
    }

    float s = s0 + s1;
    #pragma unroll
    for (int off = 32; off; off >>= 1) s += __shfl_xor(s, off);

    __syncthreads();
    if (lane == 0) sredf[wave] = s;
    __syncthreads();
    if (tid == 0)
      dn_p[blk] = (sredf[0] + sredf[1]) + (sredf[2] + sredf[3]);

    // Flag popcount: blocks 0..249 user slice, 250..499 item slice (25 uint4 each).
    if (wave == 0) {
      int cnt = 0;
      if (blk < 500 && lane < 25) {
        const uint4 v = flag4[blk * 25 + lane];
        cnt = __popc(v.x) + __popc(v.y) + __popc(v.z) + __popc(v.w);
      }
      #pragma unroll
      for (int off = 32; off; off >>= 1) cnt += __shfl_xor(cnt, off);
      if (lane == 0) {
        uc_p[blk] = (blk < 250) ? cnt : 0;
        ic_p[blk] = (blk >= 250 && blk < 500) ? cnt : 0;
      }
    }
  }

  __threadfence();
  grid.sync();

  // ---------------- Phase 3: final reduce (block 0) ----------------
  if (blk == 0) {
    float upv = up_p[tid] + up_p[tid + 256];
    float dnv = dn_p[tid] + dn_p[tid + 256];
    int   cu  = uc_p[tid] + uc_p[tid + 256];
    int   ci  = ic_p[tid] + ic_p[tid + 256];

    #pragma unroll
    for (int off = 32; off; off >>= 1) {
      upv += __shfl_xor(upv, off);
      dnv += __shfl_xor(dnv, off);
      cu  += __shfl_xor(cu, off);
      ci  += __shfl_xor(ci, off);
    }

    __shared__ float sredf2[4];
    __shared__ int   sredi2[4];
    __syncthreads();
    if (lane == 0) { sredf[wave] = upv; sredi[wave] = cu; sredf2[wave] = dnv; sredi2[wave] = ci; }
    __syncthreads();
    if (tid == 0) {
      const float usum = (sredf[0] + sredf[1]) + (sredf[2] + sredf[3]);
      const float dsum = (sredf2[0] + sredf2[1]) + (sredf2[2] + sredf2[3]);
      const int   nu   = sredi[0] + sredi[1] + sredi[2] + sredi[3];
      const int   ni   = sredi2[0] + sredi2[1] + sredi2[2] + sredi2[3];
      out[0] = -(usum / 8192.0f);
      out[1] = logf(dsum / ((float)nu * (float)ni));
    }
  }
}

// ---------------------------------------------------------------------------
// Fallback pipeline (r5, proven pass @45.7us) — used only if the cooperative
// launch is rejected. rocprof kernel names reveal which path ran.
// ---------------------------------------------------------------------------
__global__ __launch_bounds__(256) void clear_kernel(uint4* __restrict__ p) {
  const int i = blockIdx.x * 256 + threadIdx.x;
  if (i < 12500) p[i] = make_uint4(0u, 0u, 0u, 0u);
}

__global__ __launch_bounds__(256) void prep_kernel(
    const int* __restrict__ user, const int* __restrict__ pos,
    const float* __restrict__ uw, const float* __restrict__ iw,
    __hip_bfloat16* __restrict__ u_bf, __hip_bfloat16* __restrict__ p_bf,
    unsigned char* __restrict__ uflag, unsigned char* __restrict__ iflag,
    float* __restrict__ up_partials)
{
  const int wave = threadIdx.x >> 6;
  const int lane = threadIdx.x & 63;

  float upacc = 0.0f;
  for (int row = blockIdx.x * 4 + wave; row < 8192; row += 2048) {
    const int uidx = user[row];
    const int pidx = pos[row];
    float uv = uw[uidx * EMB + lane];
    float pv = iw[pidx * EMB + lane];

    float us = uv * uv, ps = pv * pv;
    #pragma unroll
    for (int off = 32; off; off >>= 1) {
      us += __shfl_xor(us, off);
      ps += __shfl_xor(ps, off);
    }
    const float un = uv / fmaxf(sqrtf(us), 1e-12f);
    const float pn = pv / fmaxf(sqrtf(ps), 1e-12f);
    u_bf[row * EMB + lane] = __float2bfloat16(un);
    p_bf[row * EMB + lane] = __float2bfloat16(pn);

    float ipv = un * pn;
    #pragma unroll
    for (int off = 32; off; off >>= 1) ipv += __shfl_xor(ipv, off);

    if (lane == 0) {
      uflag[uidx] = 1;
      iflag[pidx] = 1;
      const float t = ipv * C5LOG2E;
      upacc += logf(EXP2_HW(t) + EXP2_HW(ipv * t));
    }
  }

  __shared__ float sred[4];
  if (lane == 0) sred[wave] = upacc;
  __syncthreads();
  if (threadIdx.x == 0)
    up_partials[blockIdx.x] = (sred[0] + sred[1]) + (sred[2] + sred[3]);
}

__global__ __launch_bounds__(256) void gemm_kernel(
    const __hip_bfloat16* __restrict__ U, const __hip_bfloat16* __restrict__ P,
    float* __restrict__ down_partials)
{
  const int by  = blockIdx.x >> 4;
  const int bx0 = (blockIdx.x & 15) << 2;
  const int wave = threadIdx.x >> 6;
  const int lane = threadIdx.x & 63;
  const int r0 = by * 128 + (wave >> 1) * 64;
  const int lrow = lane & 15;
  const int lk   = (lane >> 4) * 8;

  short8 a[4][2];
  #pragma unroll
  for (int i = 0; i < 4; ++i)
    #pragma unroll
    for (int kk = 0; kk < 2; ++kk)
      a[i][kk] = *reinterpret_cast<const short8*>(
          &U[(size_t)(r0 + i * 16 + lrow) * EMB + kk * 32 + lk]);

  float s0 = 0.0f, s1 = 0.0f;
  #pragma unroll 1
  for (int t = 0; t < 4; ++t) {
    const int c0 = (bx0 + t) * 128 + (wave & 1) * 64;
    short8 b[4][2];
    #pragma unroll
    for (int j = 0; j < 4; ++j)
      #pragma unroll
      for (int kk = 0; kk < 2; ++kk)
        b[j][kk] = *reinterpret_cast<const short8*>(
            &P[(size_t)(c0 + j * 16 + lrow) * EMB + kk * 32 + lk]);

    f32x4 acc[4][4] = {};
    #pragma unroll
    for (int i = 0; i < 4; ++i)
      #pragma unroll
      for (int j = 0; j < 4; ++j) {
        acc[i][j] = mfma16x16x32(a[i][0], b[j][0], acc[i][j]);
        acc[i][j] = mfma16x16x32(a[i][1], b[j][1], acc[i][j]);
      }
    #pragma unroll
    for (int i = 0; i < 4; ++i)
      #pragma unroll
      for (int j = 0; j < 4; ++j)
        #pragma unroll
        for (int r = 0; r < 4; ++r) {
          const float v  = acc[i][j][r];
          const float tt = v * C5LOG2E;
          s0 += EXP2_HW(tt);
          s1 += EXP2_HW(v * tt);
        }
  }

  float s = s0 + s1;
  #pragma unroll
  for (int off = 32; off; off >>= 1) s += __shfl_xor(s, off);

  __shared__ float sred[4];
  if (lane == 0) sred[wave] = s;
  __syncthreads();
  if (threadIdx.x == 0)
    down_partials[blockIdx.x] = (sred[0] + sred[1]) + (sred[2] + sred[3]);
}

__global__ __launch_bounds__(1024) void finalize_kernel(
    const float* __restrict__ up_partials, const float* __restrict__ down_partials,
    const uint4* __restrict__ uflag4, const uint4* __restrict__ iflag4,
    float* __restrict__ out)
{
  const int tid  = threadIdx.x;
  const int wave = tid >> 6;
  const int lane = tid & 63;

  float upv = (tid < 512) ? up_partials[tid] : 0.0f;
  float dnv = down_partials[tid];
  int uc = 0, ic = 0;
  for (int i = tid; i < 6250; i += 1024) {
    uint4 v = uflag4[i];
    uc += __popc(v.x) + __popc(v.y) + __popc(v.z) + __popc(v.w);
    uint4 w = iflag4[i];
    ic += __popc(w.x) + __popc(w.y) + __popc(w.z) + __popc(w.w);
  }

  #pragma unroll
  for (int off = 32; off; off >>= 1) {
    upv += __shfl_xor(upv, off);
    dnv += __shfl_xor(dnv, off);
    uc  += __shfl_xor(uc, off);
    ic  += __shfl_xor(ic, off);
  }

  __shared__ float sf[2][16];
  __shared__ int   si[2][16];
  if (lane == 0) { sf[0][wave] = upv; sf[1][wave] = dnv; si[0][wave] = uc; si[1][wave] = ic; }
  __syncthreads();
  if (tid == 0) {
    float usum = 0.0f, dsum = 0.0f; int nu = 0, ni = 0;
    #pragma unroll
    for (int w = 0; w < 16; ++w) {
      usum += sf[0][w]; dsum += sf[1][w]; nu += si[0][w]; ni += si[1][w];
    }
    out[0] = -(usum / 8192.0f);
    out[1] = logf(dsum / ((float)nu * (float)ni));
  }
}

extern "C" void kernel_launch(void* const* d_in, const int* in_sizes, int n_in,
                              void* d_out, int out_size, void* d_ws, size_t ws_size,
                              hipStream_t stream) {
  const int*   user = (const int*)d_in[0];
  const int*   pos  = (const int*)d_in[1];
  // d_in[2] = negative (unused by the reference loss)
  const float* uw   = (const float*)d_in[3];
  const float* iw   = (const float*)d_in[4];
  float* out = (float*)d_out;

  char* ws = (char*)d_ws;
  __hip_bfloat16* u_bf = (__hip_bfloat16*)(ws);
  __hip_bfloat16* p_bf = (__hip_bfloat16*)(ws + (1u << 20));
  uint4* flag4 = (uint4*)(ws + (2u << 20));              // 200,000 B
  unsigned char* uflag = (unsigned char*)flag4;
  unsigned char* iflag = uflag + 100000;
  char* tail = ws + (2u << 20) + 200704;
  float* up_p = (float*)tail;                            // 512
  float* dn_p = up_p + 512;                              // 512
  int*   uc_p = (int*)(dn_p + 512);                      // 512
  int*   ic_p = uc_p + 512;                              // 512
  float* dn_fb = (float*)(ic_p + 512);                   // 1024 (fallback)

  void* args[] = { (void*)&user, (void*)&pos, (void*)&uw, (void*)&iw,
                   (void*)&u_bf, (void*)&p_bf, (void*)&flag4,
                   (void*)&up_p, (void*)&dn_p, (void*)&uc_p, (void*)&ic_p,
                   (void*)&out };
  hipError_t err = hipLaunchCooperativeKernel((const void*)fused_kernel,
                                              dim3(512), dim3(256), args, 0, stream);
  if (err != hipSuccess) {
    // Proven r5 pipeline.
    clear_kernel<<<49, 256, 0, stream>>>(flag4);
    prep_kernel<<<512, 256, 0, stream>>>(user, pos, uw, iw, u_bf, p_bf,
                                         uflag, iflag, up_p);
    gemm_kernel<<<1024, 256, 0, stream>>>(u_bf, p_bf, dn_fb);
    finalize_kernel<<<1, 1024, 0, stream>>>(up_p, dn_fb,
                                            (const uint4*)uflag,
                                            (const uint4*)iflag, out);
  }
}

// Round 10
// 54.796 us; speedup vs baseline: 4.8995x; 4.8989x over previous
//
#include <hip/hip_runtime.h>
#include <hip/hip_bf16.h>

#define EMB 64

typedef __attribute__((ext_vector_type(8))) short short8;
typedef __attribute__((ext_vector_type(8))) __bf16 bf16x8;
typedef __attribute__((ext_vector_type(4))) float f32x4;

__device__ inline f32x4 mfma16x16x32(short8 a, short8 b, f32x4 c) {
  return __builtin_amdgcn_mfma_f32_16x16x32_bf16(
      __builtin_bit_cast(bf16x8, a), __builtin_bit_cast(bf16x8, b), c, 0, 0, 0);
}

// Raw v_exp_f32 (2^x). OCML exp2f/__expf are multi-instr expansions (r2-r4).
#define EXP2_HW __builtin_amdgcn_exp2f
#define C5LOG2E 7.213475204444817f  // 5 * log2(e)

// prep: 512 blocks x 4 waves, 4 rows/wave. Gather, l2-normalize, bf16 store,
// 'up' term, and first-occurrence scan for nu/ni (~2us; replaces
// clear+flags+popcount and removes one kernel boundary).
__global__ __launch_bounds__(256) void prep_kernel(
    const int* __restrict__ user, const int* __restrict__ pos,
    const float* __restrict__ uw, const float* __restrict__ iw,
    __hip_bfloat16* __restrict__ u_bf, __hip_bfloat16* __restrict__ p_bf,
    float* __restrict__ up_p, int* __restrict__ uc_p, int* __restrict__ ic_p)
{
  const int wave = threadIdx.x >> 6;
  const int lane = threadIdx.x & 63;
  const int blk  = blockIdx.x;

  float upacc = 0.0f;
  int   ucnt = 0, icnt = 0;

  #pragma unroll 1
  for (int ii = 0; ii < 4; ++ii) {
    const int row  = blk + (((ii << 2) + wave) << 9);  // blk + 512*(4*ii+wave)
    const int uidx = user[row];
    const int pidx = pos[row];
    float uv = uw[uidx * EMB + lane];
    float pv = iw[pidx * EMB + lane];

    float us = uv * uv, ps = pv * pv;
    #pragma unroll
    for (int off = 32; off; off >>= 1) {
      us += __shfl_xor(us, off);
      ps += __shfl_xor(ps, off);
    }
    const float un = uv / fmaxf(sqrtf(us), 1e-12f);
    const float pn = pv / fmaxf(sqrtf(ps), 1e-12f);
    u_bf[row * EMB + lane] = __float2bfloat16(un);
    p_bf[row * EMB + lane] = __float2bfloat16(pn);

    float ipv = un * pn;
    #pragma unroll
    for (int off = 32; off; off >>= 1) ipv += __shfl_xor(ipv, off);

    if (lane == 0) {
      const float t = ipv * C5LOG2E;
      upacc += logf(EXP2_HW(t) + EXP2_HW(ipv * t));  // log(exp(ip/T)+exp(ip^2/T))
    }

    // First-occurrence scan (wave-parallel, 64 ids/chunk, 32KB arrays cache-resident).
    bool udup = false, idup = false;
    const int nfull = row >> 6;
    #pragma unroll 4
    for (int c = 0; c < nfull; ++c) {
      udup |= (user[(c << 6) + lane] == uidx);
      idup |= (pos [(c << 6) + lane] == pidx);
    }
    const int base = nfull << 6;
    if (base + lane < row) {
      udup |= (user[base + lane] == uidx);
      idup |= (pos [base + lane] == pidx);
    }
    ucnt += __any(udup) ? 0 : 1;   // wave-uniform
    icnt += __any(idup) ? 0 : 1;
  }

  __shared__ float sredf[4];
  __shared__ int   sredu[4], sredi[4];
  if (lane == 0) { sredf[wave] = upacc; sredu[wave] = ucnt; sredi[wave] = icnt; }
  __syncthreads();
  if (threadIdx.x == 0) {
    up_p[blk] = (sredf[0] + sredf[1]) + (sredf[2] + sredf[3]);
    uc_p[blk] = sredu[0] + sredu[1] + sredu[2] + sredu[3];
    ic_p[blk] = sredi[0] + sredi[1] + sredi[2] + sredi[3];
  }
}

// 1024 blocks = 64 row-strips x 16 col-groups x 4 tiles (r5's PROVEN grid —
// r9's bug was by=blk>>3 with 1024 blocks -> 128 row-strips, 64 of them
// garbage, doubling dsum). Interleaved epilogue: per 16-col slab j ->
// {2 loads, 8 MFMA, 32 exp}, j fully unrolled so slab j+1 loads hoist over
// slab j's exp and the trans pipe stays fed. 4 sum accumulators.
__global__ __launch_bounds__(256) void gemm_kernel(
    const __hip_bfloat16* __restrict__ U, const __hip_bfloat16* __restrict__ P,
    float* __restrict__ dn_p)
{
  const int by  = blockIdx.x >> 4;          // [0,64)
  const int bx0 = (blockIdx.x & 15) << 2;   // 4 tiles -> 64 col-tiles
  const int wave = threadIdx.x >> 6;
  const int lane = threadIdx.x & 63;
  const int r0 = by * 128 + (wave >> 1) * 64;
  const int lrow = lane & 15;
  const int lk   = (lane >> 4) * 8;

  short8 a[4][2];
  #pragma unroll
  for (int i = 0; i < 4; ++i)
    #pragma unroll
    for (int kk = 0; kk < 2; ++kk)
      a[i][kk] = *reinterpret_cast<const short8*>(
          &U[(size_t)(r0 + i * 16 + lrow) * EMB + kk * 32 + lk]);

  float s0 = 0.0f, s1 = 0.0f, s2 = 0.0f, s3 = 0.0f;

  #pragma unroll 2
  for (int t = 0; t < 4; ++t) {
    const int c0 = (bx0 + t) * 128 + (wave & 1) * 64;
    #pragma unroll
    for (int j = 0; j < 4; ++j) {
      const short8 b0 = *reinterpret_cast<const short8*>(
          &P[(size_t)(c0 + j * 16 + lrow) * EMB + lk]);
      const short8 b1 = *reinterpret_cast<const short8*>(
          &P[(size_t)(c0 + j * 16 + lrow) * EMB + 32 + lk]);

      f32x4 acc[4] = {};
      #pragma unroll
      for (int i = 0; i < 4; ++i) {
        acc[i] = mfma16x16x32(a[i][0], b0, acc[i]);
        acc[i] = mfma16x16x32(a[i][1], b1, acc[i]);
      }

      // exp(v/T)=2^(v*C); exp(v^2/T)=2^(v*(v*C)); |v|<=~1.
      #pragma unroll
      for (int i = 0; i < 4; ++i) {
        #pragma unroll
        for (int r = 0; r < 4; ++r) {
          const float v  = acc[i][r];
          const float tt = v * C5LOG2E;
          if (i & 1) { s2 += EXP2_HW(tt); s3 += EXP2_HW(v * tt); }
          else       { s0 += EXP2_HW(tt); s1 += EXP2_HW(v * tt); }
        }
      }
    }
  }

  float s = (s0 + s1) + (s2 + s3);
  #pragma unroll
  for (int off = 32; off; off >>= 1) s += __shfl_xor(s, off);

  __shared__ float sred[4];
  if (lane == 0) sred[wave] = s;
  __syncthreads();
  if (threadIdx.x == 0)
    dn_p[blockIdx.x] = (sred[0] + sred[1]) + (sred[2] + sred[3]);
}

// Single-block deterministic final reduction.
__global__ __launch_bounds__(1024) void finalize_kernel(
    const float* __restrict__ up_p, const float* __restrict__ dn_p,
    const int* __restrict__ uc_p, const int* __restrict__ ic_p,
    float* __restrict__ out)
{
  const int tid  = threadIdx.x;
  const int wave = tid >> 6;
  const int lane = tid & 63;

  float upv = (tid < 512) ? up_p[tid] : 0.0f;
  float dnv = dn_p[tid];                       // exactly 1024 partials
  int   uc  = (tid < 512) ? uc_p[tid] : 0;
  int   ic  = (tid < 512) ? ic_p[tid] : 0;

  #pragma unroll
  for (int off = 32; off; off >>= 1) {
    upv += __shfl_xor(upv, off);
    dnv += __shfl_xor(dnv, off);
    uc  += __shfl_xor(uc, off);
    ic  += __shfl_xor(ic, off);
  }

  __shared__ float sf[2][16];
  __shared__ int   si[2][16];
  if (lane == 0) { sf[0][wave] = upv; sf[1][wave] = dnv; si[0][wave] = uc; si[1][wave] = ic; }
  __syncthreads();
  if (tid == 0) {
    float usum = 0.0f, dsum = 0.0f; int nu = 0, ni = 0;
    #pragma unroll
    for (int w = 0; w < 16; ++w) {
      usum += sf[0][w]; dsum += sf[1][w]; nu += si[0][w]; ni += si[1][w];
    }
    out[0] = -(usum / 8192.0f);
    out[1] = logf(dsum / ((float)nu * (float)ni));
  }
}

extern "C" void kernel_launch(void* const* d_in, const int* in_sizes, int n_in,
                              void* d_out, int out_size, void* d_ws, size_t ws_size,
                              hipStream_t stream) {
  const int*   user = (const int*)d_in[0];
  const int*   pos  = (const int*)d_in[1];
  // d_in[2] = negative (unused by the reference loss)
  const float* uw   = (const float*)d_in[3];
  const float* iw   = (const float*)d_in[4];
  float* out = (float*)d_out;

  char* ws = (char*)d_ws;
  __hip_bfloat16* u_bf = (__hip_bfloat16*)(ws);
  __hip_bfloat16* p_bf = (__hip_bfloat16*)(ws + (1u << 20));
  float* up_p = (float*)(ws + (2u << 20));   // 512
  float* dn_p = up_p + 512;                  // 1024
  int*   uc_p = (int*)(dn_p + 1024);         // 512
  int*   ic_p = uc_p + 512;                  // 512

  prep_kernel<<<512, 256, 0, stream>>>(user, pos, uw, iw, u_bf, p_bf,
                                       up_p, uc_p, ic_p);
  gemm_kernel<<<1024, 256, 0, stream>>>(u_bf, p_bf, dn_p);
  finalize_kernel<<<1, 1024, 0, stream>>>(up_p, dn_p, uc_p, ic_p, out);
}

// Round 11
// 45.049 us; speedup vs baseline: 5.9596x; 1.2164x over previous
//
#include <hip/hip_runtime.h>
#include <hip/hip_bf16.h>

#define EMB 64

typedef __attribute__((ext_vector_type(8))) short short8;
typedef __attribute__((ext_vector_type(8))) __bf16 bf16x8;
typedef __attribute__((ext_vector_type(4))) float f32x4;

__device__ inline f32x4 mfma16x16x32(short8 a, short8 b, f32x4 c) {
  return __builtin_amdgcn_mfma_f32_16x16x32_bf16(
      __builtin_bit_cast(bf16x8, a), __builtin_bit_cast(bf16x8, b), c, 0, 0, 0);
}

// Raw v_exp_f32 (2^x). OCML exp2f/__expf are multi-instr expansions (r2-r4).
#define EXP2_HW __builtin_amdgcn_exp2f
#define C5LOG2E 7.213475204444817f  // 5 * log2(e)

// Clears the 200,000-byte flag region (12,500 uint4).
__global__ __launch_bounds__(256) void clear_kernel(uint4* __restrict__ p) {
  const int i = blockIdx.x * 256 + threadIdx.x;
  if (i < 12500) p[i] = make_uint4(0u, 0u, 0u, 0u);
}

// prep: 512 blocks x 16 rows. 16-lane-group float4 layout: each wave handles
// 4 rows in parallel (lane = g*16+e, row-sub g, elems e*4..e*4+3). One float4
// gather per table per lane, 4-step shuffle reduces. Flags scatter for nu/ni
// (the r9/r10 O(B^2) scan read ~268MB from L2 — flags+popcount are ~100x
// cheaper in traffic).
__global__ __launch_bounds__(256) void prep_kernel(
    const int* __restrict__ user, const int* __restrict__ pos,
    const float* __restrict__ uw, const float* __restrict__ iw,
    __hip_bfloat16* __restrict__ u_bf, __hip_bfloat16* __restrict__ p_bf,
    unsigned char* __restrict__ uflag, unsigned char* __restrict__ iflag,
    float* __restrict__ up_p)
{
  const int tid  = threadIdx.x;
  const int wave = tid >> 6;
  const int lane = tid & 63;
  const int e    = lane & 15;          // element group within row
  const int row  = blockIdx.x * 16 + wave * 4 + (lane >> 4);

  const int uidx = user[row];          // same addr across 16-lane group: broadcast
  const int pidx = pos[row];
  const float4 uv = *reinterpret_cast<const float4*>(&uw[(size_t)uidx * EMB + e * 4]);
  const float4 pv = *reinterpret_cast<const float4*>(&iw[(size_t)pidx * EMB + e * 4]);

  float us = uv.x*uv.x + uv.y*uv.y + uv.z*uv.z + uv.w*uv.w;
  float ps = pv.x*pv.x + pv.y*pv.y + pv.z*pv.z + pv.w*pv.w;
  #pragma unroll
  for (int off = 1; off < 16; off <<= 1) {
    us += __shfl_xor(us, off);
    ps += __shfl_xor(ps, off);
  }
  const float ur = 1.0f / fmaxf(sqrtf(us), 1e-12f);
  const float pr = 1.0f / fmaxf(sqrtf(ps), 1e-12f);
  const float4 un = make_float4(uv.x*ur, uv.y*ur, uv.z*ur, uv.w*ur);
  const float4 pn = make_float4(pv.x*pr, pv.y*pr, pv.z*pr, pv.w*pr);

  ushort4 ub, pb;
  ub.x = __bfloat16_as_ushort(__float2bfloat16(un.x));
  ub.y = __bfloat16_as_ushort(__float2bfloat16(un.y));
  ub.z = __bfloat16_as_ushort(__float2bfloat16(un.z));
  ub.w = __bfloat16_as_ushort(__float2bfloat16(un.w));
  pb.x = __bfloat16_as_ushort(__float2bfloat16(pn.x));
  pb.y = __bfloat16_as_ushort(__float2bfloat16(pn.y));
  pb.z = __bfloat16_as_ushort(__float2bfloat16(pn.z));
  pb.w = __bfloat16_as_ushort(__float2bfloat16(pn.w));
  *reinterpret_cast<ushort4*>(&u_bf[(size_t)row * EMB + e * 4]) = ub;
  *reinterpret_cast<ushort4*>(&p_bf[(size_t)row * EMB + e * 4]) = pb;

  float ip = un.x*pn.x + un.y*pn.y + un.z*pn.z + un.w*pn.w;
  #pragma unroll
  for (int off = 1; off < 16; off <<= 1) ip += __shfl_xor(ip, off);

  float upv = 0.0f;
  if (e == 0) {
    uflag[uidx] = 1;
    iflag[pidx] = 1;
    const float t = ip * C5LOG2E;
    upv = logf(EXP2_HW(t) + EXP2_HW(ip * t));  // log(exp(ip/T)+exp(ip^2/T))
  }
  // sum the 4 per-row values (lanes 0,16,32,48) across the wave
  upv += __shfl_xor(upv, 16);
  upv += __shfl_xor(upv, 32);

  __shared__ float sred[4];
  if (lane == 0) sred[wave] = upv;
  __syncthreads();
  if (tid == 0)
    up_p[blockIdx.x] = (sred[0] + sred[1]) + (sred[2] + sred[3]);
}

// 1024 blocks = 64 row-strips x 16 col-groups x 4 tiles (proven grid).
// Burst epilogue (r5 shape — r10's per-slab interleave stalled on MFMA
// latency) + rotated B-prefetch: tile t+1's loads issue right after tile t's
// MFMAs free the b registers, and the ~1300cy exp epilogue hides their L2
// latency. Zero VGPR growth (single b buffer).
__global__ __launch_bounds__(256) void gemm_kernel(
    const __hip_bfloat16* __restrict__ U, const __hip_bfloat16* __restrict__ P,
    float* __restrict__ dn_p)
{
  const int by  = blockIdx.x >> 4;          // [0,64)
  const int bx0 = (blockIdx.x & 15) << 2;   // 4 tiles -> 64 col-tiles
  const int wave = threadIdx.x >> 6;
  const int lane = threadIdx.x & 63;
  const int r0 = by * 128 + (wave >> 1) * 64;
  const int lrow = lane & 15;
  const int lk   = (lane >> 4) * 8;

  short8 a[4][2];
  #pragma unroll
  for (int i = 0; i < 4; ++i)
    #pragma unroll
    for (int kk = 0; kk < 2; ++kk)
      a[i][kk] = *reinterpret_cast<const short8*>(
          &U[(size_t)(r0 + i * 16 + lrow) * EMB + kk * 32 + lk]);

  short8 b[4][2];
  auto loadB = [&](int t) {
    const int c0 = (bx0 + t) * 128 + (wave & 1) * 64;
    #pragma unroll
    for (int j = 0; j < 4; ++j)
      #pragma unroll
      for (int kk = 0; kk < 2; ++kk)
        b[j][kk] = *reinterpret_cast<const short8*>(
            &P[(size_t)(c0 + j * 16 + lrow) * EMB + kk * 32 + lk]);
  };

  float s0 = 0.0f, s1 = 0.0f, s2 = 0.0f, s3 = 0.0f;

  loadB(0);
  #pragma unroll 1
  for (int t = 0; t < 4; ++t) {
    f32x4 acc[4][4] = {};
    #pragma unroll
    for (int i = 0; i < 4; ++i)
      #pragma unroll
      for (int j = 0; j < 4; ++j) {
        acc[i][j] = mfma16x16x32(a[i][0], b[j][0], acc[i][j]);
        acc[i][j] = mfma16x16x32(a[i][1], b[j][1], acc[i][j]);
      }

    // Prefetch next tile's B into the (now free) b registers; the epilogue
    // below covers the load latency. t=3 reloads tile 0 (harmless).
    loadB((t + 1) & 3);

    // exp(v/T)=2^(v*C); exp(v^2/T)=2^(v*(v*C)); |v|<=~1.
    #pragma unroll
    for (int i = 0; i < 4; ++i)
      #pragma unroll
      for (int j = 0; j < 4; ++j)
        #pragma unroll
        for (int r = 0; r < 4; ++r) {
          const float v  = acc[i][j][r];
          const float tt = v * C5LOG2E;
          if (j & 1) { s2 += EXP2_HW(tt); s3 += EXP2_HW(v * tt); }
          else       { s0 += EXP2_HW(tt); s1 += EXP2_HW(v * tt); }
        }
  }

  float s = (s0 + s1) + (s2 + s3);
  #pragma unroll
  for (int off = 32; off; off >>= 1) s += __shfl_xor(s, off);

  __shared__ float sred[4];
  if (lane == 0) sred[wave] = s;
  __syncthreads();
  if (threadIdx.x == 0)
    dn_p[blockIdx.x] = (sred[0] + sred[1]) + (sred[2] + sred[3]);
}

// Single-block deterministic final reduction (r5-proven shape).
__global__ __launch_bounds__(1024) void finalize_kernel(
    const float* __restrict__ up_p, const float* __restrict__ dn_p,
    const uint4* __restrict__ uflag4, const uint4* __restrict__ iflag4,
    float* __restrict__ out)
{
  const int tid  = threadIdx.x;
  const int wave = tid >> 6;
  const int lane = tid & 63;

  float upv = (tid < 512) ? up_p[tid] : 0.0f;
  float dnv = dn_p[tid];                       // exactly 1024 partials
  int uc = 0, ic = 0;
  for (int i = tid; i < 6250; i += 1024) {     // 100000 B = 6250 * 16
    uint4 v = uflag4[i];
    uc += __popc(v.x) + __popc(v.y) + __popc(v.z) + __popc(v.w);
    uint4 w = iflag4[i];
    ic += __popc(w.x) + __popc(w.y) + __popc(w.z) + __popc(w.w);
  }

  #pragma unroll
  for (int off = 32; off; off >>= 1) {
    upv += __shfl_xor(upv, off);
    dnv += __shfl_xor(dnv, off);
    uc  += __shfl_xor(uc, off);
    ic  += __shfl_xor(ic, off);
  }

  __shared__ float sf[2][16];
  __shared__ int   si[2][16];
  if (lane == 0) { sf[0][wave] = upv; sf[1][wave] = dnv; si[0][wave] = uc; si[1][wave] = ic; }
  __syncthreads();
  if (tid == 0) {
    float usum = 0.0f, dsum = 0.0f; int nu = 0, ni = 0;
    #pragma unroll
    for (int w = 0; w < 16; ++w) {
      usum += sf[0][w]; dsum += sf[1][w]; nu += si[0][w]; ni += si[1][w];
    }
    out[0] = -(usum / 8192.0f);
    out[1] = logf(dsum / ((float)nu * (float)ni));
  }
}

extern "C" void kernel_launch(void* const* d_in, const int* in_sizes, int n_in,
                              void* d_out, int out_size, void* d_ws, size_t ws_size,
                              hipStream_t stream) {
  const int*   user = (const int*)d_in[0];
  const int*   pos  = (const int*)d_in[1];
  // d_in[2] = negative (unused by the reference loss)
  const float* uw   = (const float*)d_in[3];
  const float* iw   = (const float*)d_in[4];
  float* out = (float*)d_out;

  char* ws = (char*)d_ws;
  __hip_bfloat16* u_bf = (__hip_bfloat16*)(ws);
  __hip_bfloat16* p_bf = (__hip_bfloat16*)(ws + (1u << 20));
  uint4* flag4 = (uint4*)(ws + (2u << 20));              // 200,000 B
  unsigned char* uflag = (unsigned char*)flag4;
  unsigned char* iflag = uflag + 100000;
  float* up_p = (float*)(ws + (2u << 20) + 200704);      // 512
  float* dn_p = up_p + 512;                              // 1024

  clear_kernel<<<49, 256, 0, stream>>>(flag4);
  prep_kernel<<<512, 256, 0, stream>>>(user, pos, uw, iw, u_bf, p_bf,
                                       uflag, iflag, up_p);
  gemm_kernel<<<1024, 256, 0, stream>>>(u_bf, p_bf, dn_p);
  finalize_kernel<<<1, 1024, 0, stream>>>(up_p, dn_p,
                                          (const uint4*)uflag,
                                          (const uint4*)iflag, out);
}